// Round 15
// baseline (44.660 us; speedup 1.0000x reference)
//
#include <hip/hip_runtime.h>
#include <hip/hip_fp16.h>

#define NN 8
#define MM 8
#define NH1 64
#define NH2 32

#define FOR8(OP) OP(0) OP(1) OP(2) OP(3) OP(4) OP(5) OP(6) OP(7)

typedef float v2f  __attribute__((ext_vector_type(2)));
typedef float sf16 __attribute__((ext_vector_type(16)));
typedef __fp16 h2f __attribute__((ext_vector_type(2)));

// ---- scalar-pipe streaming: split ISSUE (no wait) / WAIT (tied to data) ----
#define S_ISSUE2(d0, d1, base, imm)                                    \
    asm volatile("s_load_dwordx16 %0, %2, %c3\n\t"                     \
                 "s_load_dwordx16 %1, %2, %c4"                         \
                 : "=&s"(d0), "=&s"(d1)                                \
                 : "s"(base), "n"(imm), "n"((imm) + 64))

#define S_ISSUE1(d0, base, imm)                                        \
    asm volatile("s_load_dwordx16 %0, %1, %c2"                         \
                 : "=&s"(d0) : "s"(base), "n"(imm))

#define S_WAIT2(d0, d1)                                                \
    asm volatile("s_waitcnt lgkmcnt(0)" : "+s"(d0), "+s"(d1))

#define S_WAIT1(d0)                                                    \
    asm volatile("s_waitcnt lgkmcnt(0)" : "+s"(d0))

// acc += w * xi, packed f32; w is the one SGPR-pair operand (folded).
#define PKFMA(acc, w, xi)                                              \
    asm("v_pk_fma_f32 %0, %1, %2, %0" : "+v"(acc) : "s"(w), "v"(xi))

// acc += dot2(f16pair(hp), f16pair(w)); w folded from SGPR.
#define DOT2(acc, w, hp)                                               \
    asm("v_dot2_f32_f16 %0, %2, %1, %0" : "+v"(acc) : "s"(w), "v"(hp))

// =====================================================================
// Prep: pack W21 (ONLY — the error-tolerant p path) as f16 pairs along K.
//   ws[k2*32 + j] = f16(W21[2k2][j]) | f16(W21[2k2+1][j])<<16
// =====================================================================
__global__ void prep_f16(const float* __restrict__ W21,
                         unsigned int* __restrict__ ws)
{
    const int t = blockIdx.x * 256 + threadIdx.x;     // 0..1023
    const int k2 = t >> 5, j = t & 31;
    const float lo = W21[(2 * k2) * NH2 + j];
    const float hi = W21[(2 * k2 + 1) * NH2 + j];
    const __half hlo = __float2half(lo), hhi = __float2half(hi);  // RNE
    ws[t] = ((unsigned int)__half_as_ushort(hhi) << 16) | __half_as_ushort(hlo);
}

__device__ __forceinline__ void compute_row(
    int row,
    const float* __restrict__ x_g,
    const float* __restrict__ W1,  const float* __restrict__ b1,
    const float* __restrict__ ws21,
    const float* __restrict__ b21, const float* __restrict__ b22,
    const float* __restrict__ W22,
    const float* __restrict__ W31, const float* __restrict__ b31,
    const float* __restrict__ W32, const float* __restrict__ b32,
    const float* __restrict__ Amat, const float* __restrict__ Gmat,
    const float* __restrict__ mean, const float* __restrict__ std_,
    float* __restrict__ out)
{
    // ---- load x (per-lane, vectorized) ----
    float x[NN];
    {
        const float4* xv = reinterpret_cast<const float4*>(x_g + (size_t)row * NN);
        float4 a0 = xv[0], a1 = xv[1];
        x[0] = a0.x; x[1] = a0.y; x[2] = a0.z; x[3] = a0.w;
        x[4] = a1.x; x[5] = a1.y; x[6] = a1.z; x[7] = a1.w;
    }

    // ---- un-normalized state ----
    float x0[NN];
    {
        const float4 sd0 = ((const float4*)std_)[0], sd1 = ((const float4*)std_)[1];
        const float4 mn0 = ((const float4*)mean)[0], mn1 = ((const float4*)mean)[1];
        x0[0] = fmaf(x[0], sd0.x, mn0.x); x0[1] = fmaf(x[1], sd0.y, mn0.y);
        x0[2] = fmaf(x[2], sd0.z, mn0.z); x0[3] = fmaf(x[3], sd0.w, mn0.w);
        x0[4] = fmaf(x[4], sd1.x, mn1.x); x0[5] = fmaf(x[5], sd1.y, mn1.y);
        x0[6] = fmaf(x[6], sd1.z, mn1.z); x0[7] = fmaf(x[7], sd1.w, mn1.w);
    }

    // =====================================================================
    // Layer 1 (f32, exact — identical to round 12): depth-1 pipelined
    // scalar stream of W1, packed-f32 FMA.
    // =====================================================================
    v2f hv[NH1 / 2];
#pragma unroll
    for (int j2 = 0; j2 < NH1 / 2; ++j2) hv[j2] = *(const v2f*)(b1 + 2 * j2);

    {
        sf16 rA0, rA1, rB0, rB1;
        S_ISSUE2(rA0, rA1, W1, 0);
        S_WAIT2(rA0, rA1);
#pragma unroll
        for (int u = 0; u < 16; ++u) {
            const int i = u >> 1, hh = u & 1;
            const v2f xi = { x[i], x[i] };
            if ((u & 1) == 0) {
                if (u + 1 < 16) S_ISSUE2(rB0, rB1, W1, (u + 1) * 128);
#pragma unroll
                for (int j2 = 0; j2 < 8; ++j2) { const v2f w = { rA0[2*j2], rA0[2*j2+1] }; PKFMA(hv[hh*16 + j2], w, xi); }
#pragma unroll
                for (int j2 = 0; j2 < 8; ++j2) { const v2f w = { rA1[2*j2], rA1[2*j2+1] }; PKFMA(hv[hh*16 + 8 + j2], w, xi); }
                if (u + 1 < 16) S_WAIT2(rB0, rB1);
            } else {
                if (u + 1 < 16) S_ISSUE2(rA0, rA1, W1, (u + 1) * 128);
#pragma unroll
                for (int j2 = 0; j2 < 8; ++j2) { const v2f w = { rB0[2*j2], rB0[2*j2+1] }; PKFMA(hv[hh*16 + j2], w, xi); }
#pragma unroll
                for (int j2 = 0; j2 < 8; ++j2) { const v2f w = { rB1[2*j2], rB1[2*j2+1] }; PKFMA(hv[hh*16 + 8 + j2], w, xi); }
                if (u + 1 < 16) S_WAIT2(rA0, rA1);
            }
        }
    }
    {
        const v2f zero2 = { 0.0f, 0.0f };
#pragma unroll
        for (int j2 = 0; j2 < NH1 / 2; ++j2) hv[j2] = __builtin_elementwise_max(hv[j2], zero2);
    }

    // =====================================================================
    // a22 pass (f32, EXACT — same chains as round 12): the alpha/c0 path
    // is error-amplified (x hx x lambda), so it stays full precision.
    // =====================================================================
    v2f a22[NH2 / 2];
#pragma unroll
    for (int j2 = 0; j2 < NH2 / 2; ++j2) a22[j2] = *(const v2f*)(b22 + 2 * j2);
    {
        sf16 qA0, qA1, qB0, qB1;
        S_ISSUE2(qA0, qA1, W22, 0);
        S_WAIT2(qA0, qA1);
#pragma unroll
        for (int k = 0; k < NH1; ++k) {
            const v2f hb = (k & 1) ? hv[k >> 1].yy : hv[k >> 1].xx;
            if ((k & 1) == 0) {
                if (k + 1 < NH1) S_ISSUE2(qB0, qB1, W22, (k + 1) * 128);
#pragma unroll
                for (int j2 = 0; j2 < 8; ++j2) { const v2f w = { qA0[2*j2], qA0[2*j2+1] }; PKFMA(a22[j2], w, hb); }
#pragma unroll
                for (int j2 = 0; j2 < 8; ++j2) { const v2f w = { qA1[2*j2], qA1[2*j2+1] }; PKFMA(a22[8 + j2], w, hb); }
                if (k + 1 < NH1) S_WAIT2(qB0, qB1);
            } else {
                if (k + 1 < NH1) S_ISSUE2(qA0, qA1, W22, (k + 1) * 128);
#pragma unroll
                for (int j2 = 0; j2 < 8; ++j2) { const v2f w = { qB0[2*j2], qB0[2*j2+1] }; PKFMA(a22[j2], w, hb); }
#pragma unroll
                for (int j2 = 0; j2 < 8; ++j2) { const v2f w = { qB1[2*j2], qB1[2*j2+1] }; PKFMA(a22[8 + j2], w, hb); }
                if (k + 1 < NH1) S_WAIT2(qA0, qA1);
            }
        }
    }

    // ---- alpha-head (f32 exact, k ascending — same chain as round 12) ----
    sf16 wA0, wA1;
    S_ISSUE2(wA0, wA1, W32, 0);
    {
        const v2f zero2 = { 0.0f, 0.0f };
#pragma unroll
        for (int j2 = 0; j2 < NH2 / 2; ++j2) a22[j2] = __builtin_elementwise_max(a22[j2], zero2);
    }
    S_WAIT2(wA0, wA1);
    float s = b32[0];
#pragma unroll
    for (int k = 0; k < 16; ++k)
        s = fmaf((k & 1) ? a22[k >> 1].y : a22[k >> 1].x, wA0[k], s);
#pragma unroll
    for (int k = 16; k < 32; ++k)
        s = fmaf((k & 1) ? a22[k >> 1].y : a22[k >> 1].x, wA1[k - 16], s);
    const float alphax = 4.0f / (1.0f + __expf(-s));
    // a22 dead from here -> register pressure drops before the a21 phase.

    // ---- pack h into f16 pairs (frees hv after this phase) ----
    float hpk[NH1 / 2];
#pragma unroll
    for (int k2 = 0; k2 < NH1 / 2; ++k2) {
        h2f hp = __builtin_amdgcn_cvt_pkrtz(hv[k2].x, hv[k2].y);
        hpk[k2] = __builtin_bit_cast(float, hp);
    }

    // =====================================================================
    // a21 pass (f16 dot2 — the p path tolerates ~1e-3 quantization).
    // 32 pipelined 128B batches; 32 dot2 (64 cy) cover per batch.
    // =====================================================================
    float a21s[NH2];
#pragma unroll
    for (int j4 = 0; j4 < NH2 / 4; ++j4) {
        const float4 i21 = ((const float4*)b21)[j4];
        a21s[4*j4]   = i21.x; a21s[4*j4+1] = i21.y;
        a21s[4*j4+2] = i21.z; a21s[4*j4+3] = i21.w;
    }
    {
        sf16 A0, A1, B0, B1;
        S_ISSUE2(A0, A1, ws21, 0);
        S_WAIT2(A0, A1);
#pragma unroll
        for (int k2 = 0; k2 < 32; ++k2) {
            const float hp = hpk[k2];
            if ((k2 & 1) == 0) {
                if (k2 + 1 < 32) S_ISSUE2(B0, B1, ws21, (k2 + 1) * 128);
#pragma unroll
                for (int j = 0; j < 16; ++j) DOT2(a21s[j],      A0[j], hp);
#pragma unroll
                for (int j = 0; j < 16; ++j) DOT2(a21s[16 + j], A1[j], hp);
                if (k2 + 1 < 32) S_WAIT2(B0, B1);
            } else {
                if (k2 + 1 < 32) S_ISSUE2(A0, A1, ws21, (k2 + 1) * 128);
#pragma unroll
                for (int j = 0; j < 16; ++j) DOT2(a21s[j],      B0[j], hp);
#pragma unroll
                for (int j = 0; j < 16; ++j) DOT2(a21s[16 + j], B1[j], hp);
                if (k2 + 1 < 32) S_WAIT2(A0, A1);
            }
        }
    }
#pragma unroll
    for (int j = 0; j < NH2; ++j) a21s[j] = fmaxf(a21s[j], 0.0f);

    // ---- p-head (f32, scalar-pipe, pipelined) ----
    v2f pv[MM / 2];
#pragma unroll
    for (int j2 = 0; j2 < MM / 2; ++j2) pv[j2] = *(const v2f*)(b31 + 2 * j2);
    {
        sf16 pA, pB;
        S_ISSUE1(pA, W31, 0);
        S_WAIT1(pA);
#pragma unroll
        for (int k2 = 0; k2 < NH2 / 2; ++k2) {
            const v2f ha  = { a21s[2*k2],     a21s[2*k2]     };
            const v2f hb2 = { a21s[2*k2 + 1], a21s[2*k2 + 1] };
            if ((k2 & 1) == 0) {
                if (k2 + 1 < 16) S_ISSUE1(pB, W31, (k2 + 1) * 64);
#pragma unroll
                for (int j2 = 0; j2 < 4; ++j2) { const v2f w = { pA[2*j2], pA[2*j2+1] }; PKFMA(pv[j2], w, ha); }
#pragma unroll
                for (int j2 = 0; j2 < 4; ++j2) { const v2f w = { pA[8 + 2*j2], pA[8 + 2*j2+1] }; PKFMA(pv[j2], w, hb2); }
                if (k2 + 1 < 16) S_WAIT1(pB);
            } else {
                if (k2 + 1 < 16) S_ISSUE1(pA, W31, (k2 + 1) * 64);
#pragma unroll
                for (int j2 = 0; j2 < 4; ++j2) { const v2f w = { pB[2*j2], pB[2*j2+1] }; PKFMA(pv[j2], w, ha); }
#pragma unroll
                for (int j2 = 0; j2 < 4; ++j2) { const v2f w = { pB[8 + 2*j2], pB[8 + 2*j2+1] }; PKFMA(pv[j2], w, hb2); }
                if (k2 + 1 < 16) S_WAIT1(pA);
            }
        }
    }

    // ---- barrier terms (f32 exact) ----
    float hx = 16.0f;
#pragma unroll
    for (int i = 0; i < NN; ++i) hx = fmaf(-x0[i], x0[i], hx);

    float dh[NN];
#pragma unroll
    for (int i = 0; i < NN; ++i) dh[i] = -2.0f * x0[i];

    float Lfhx = 0.0f;
#pragma unroll
    for (int i = 0; i < NN; ++i) {
        const float4 aq0 = *(const float4*)(Amat + i * NN);
        const float4 aq1 = *(const float4*)(Amat + i * NN + 4);
        float fx = 0.0f;
        fx = fmaf(aq0.x, x0[0], fx); fx = fmaf(aq0.y, x0[1], fx);
        fx = fmaf(aq0.z, x0[2], fx); fx = fmaf(aq0.w, x0[3], fx);
        fx = fmaf(aq1.x, x0[4], fx); fx = fmaf(aq1.y, x0[5], fx);
        fx = fmaf(aq1.z, x0[6], fx); fx = fmaf(aq1.w, x0[7], fx);
        Lfhx = fmaf(dh[i], fx, Lfhx);
    }

#define GDECL(j) float g##j = 0.0f;
    FOR8(GDECL)
#undef GDECL
#pragma unroll
    for (int i = 0; i < NN; ++i) {
        const float4 gq0 = *(const float4*)(Gmat + i * MM);
        const float4 gq1 = *(const float4*)(Gmat + i * MM + 4);
        const float da = dh[i];
        g0 = fmaf(da, gq0.x, g0); g1 = fmaf(da, gq0.y, g1);
        g2 = fmaf(da, gq0.z, g2); g3 = fmaf(da, gq0.w, g3);
        g4 = fmaf(da, gq1.x, g4); g5 = fmaf(da, gq1.y, g5);
        g6 = fmaf(da, gq1.z, g6); g7 = fmaf(da, gq1.w, g7);
    }

    const float c0 = fmaf(alphax, hx, Lfhx);

    // =====================================================================
    // QP via exact piecewise-linear root isolation — fully scalarized.
    // =====================================================================
#define DECL_PG(j) const float p##j = (j & 1) ? pv[j >> 1].y : pv[j >> 1].x;
    FOR8(DECL_PG)
#undef DECL_PG

    auto c_of = [&](float lam) -> float {
        float c = c0;
#define CTERM(j) { float u = fmaf(lam, g##j, -p##j);                  \
                   u = fminf(fmaxf(u, -1.0f), 1.0f);                  \
                   c = fmaf(g##j, u, c); }
        FOR8(CTERM)
#undef CTERM
        return c;
    };

    const bool viol = (c_of(0.0f) < 0.0f);

    const float BIGR = 3.0e38f;         // sentinel: no right bracket found
    float lamL = 0.0f, lamR = BIGR;
#define BP(j) {                                                        \
        const float rg = __builtin_amdgcn_rcpf(g##j);                  \
        const float bpa = (p##j - 1.0f) * rg;                          \
        const float bpb = (p##j + 1.0f) * rg;                          \
        const float ca = c_of(bpa);                                    \
        const float cb = c_of(bpb);                                    \
        lamL = (bpa > 0.0f && ca <  0.0f && bpa > lamL) ? bpa : lamL;  \
        lamR = (bpa > 0.0f && ca >= 0.0f && bpa < lamR) ? bpa : lamR;  \
        lamL = (bpb > 0.0f && cb <  0.0f && bpb > lamL) ? bpb : lamL;  \
        lamR = (bpb > 0.0f && cb >= 0.0f && bpb < lamR) ? bpb : lamR;  \
    }
    FOR8(BP)
#undef BP

    const bool infeas = (lamR == BIGR);
    float lam_t = infeas ? 1.099511627776e12f : 0.5f * (lamL + lamR);
    lam_t = viol ? lam_t : 0.0f;

    float denom = 0.0f, num = c0;
#define ASET(j)                                                        \
    const float ur##j = fmaf(lam_t, g##j, -p##j);                      \
    const bool lo##j = (ur##j <= -1.0f);                               \
    const bool hi##j = (ur##j >=  1.0f);                               \
    denom += (!(lo##j || hi##j)) ? g##j * g##j : 0.0f;                 \
    num   += lo##j ? -g##j : (hi##j ? g##j : -g##j * p##j);
    FOR8(ASET)
#undef ASET

    const float lam = viol ? (-num / (denom + 1e-12f)) : 0.0f;

#define UOUT(j) const float uo##j =                                    \
    lo##j ? -1.0f : (hi##j ? 1.0f : fmaf(lam, g##j, -p##j));
    FOR8(UOUT)
#undef UOUT

    float4* ov = reinterpret_cast<float4*>(out + (size_t)row * MM);
    ov[0] = make_float4(uo0, uo1, uo2, uo3);
    ov[1] = make_float4(uo4, uo5, uo6, uo7);
}

#define ARGS_DECL                                                       \
    const float* __restrict__ x_g,                                      \
    const float* __restrict__ W1,  const float* __restrict__ b1,        \
    const float* __restrict__ ws21,                                     \
    const float* __restrict__ b21, const float* __restrict__ b22,       \
    const float* __restrict__ W22,                                      \
    const float* __restrict__ W31, const float* __restrict__ b31,       \
    const float* __restrict__ W32, const float* __restrict__ b32,       \
    const float* __restrict__ Amat, const float* __restrict__ Gmat,     \
    const float* __restrict__ mean, const float* __restrict__ std_,    \
    float* __restrict__ out
#define ARGS_PASS x_g, W1, b1, ws21, b21, b22, W22, W31, b31, W32, b32, \
                  Amat, Gmat, mean, std_, out

__global__ __launch_bounds__(256, 4) void barrier_policy_clean(ARGS_DECL)
{
    const int row = blockIdx.x * 256 + threadIdx.x;
    compute_row(row, ARGS_PASS);
}

__global__ __launch_bounds__(256, 4) void barrier_policy_guard(ARGS_DECL, int B)
{
    const int row = blockIdx.x * 256 + threadIdx.x;
    if (row < B) compute_row(row, ARGS_PASS);
}

extern "C" void kernel_launch(void* const* d_in, const int* in_sizes, int n_in,
                              void* d_out, int out_size, void* d_ws, size_t ws_size,
                              hipStream_t stream) {
    const float* x    = (const float*)d_in[0];
    const float* W1   = (const float*)d_in[1];
    const float* b1   = (const float*)d_in[2];
    const float* W21  = (const float*)d_in[3];
    const float* b21  = (const float*)d_in[4];
    const float* W22  = (const float*)d_in[5];
    const float* b22  = (const float*)d_in[6];
    const float* W31  = (const float*)d_in[7];
    const float* b31  = (const float*)d_in[8];
    const float* W32  = (const float*)d_in[9];
    const float* b32  = (const float*)d_in[10];
    const float* Amat = (const float*)d_in[11];
    const float* Gmat = (const float*)d_in[12];
    const float* mean = (const float*)d_in[13];
    const float* std_ = (const float*)d_in[14];
    float* out = (float*)d_out;

    // pack W21 (only) to f16-pair stream in workspace (4 KB)
    prep_f16<<<4, 256, 0, stream>>>(W21, (unsigned int*)d_ws);
    const float* ws21 = (const float*)d_ws;

    const int B = in_sizes[0] / NN;
    if (B % 256 == 0) {
        barrier_policy_clean<<<B / 256, 256, 0, stream>>>(
            x, W1, b1, ws21, b21, b22, W22, W31, b31, W32, b32,
            Amat, Gmat, mean, std_, out);
    } else {
        barrier_policy_guard<<<(B + 255) / 256, 256, 0, stream>>>(
            x, W1, b1, ws21, b21, b22, W22, W31, b31, W32, b32,
            Amat, Gmat, mean, std_, out, B);
    }
}